// Round 11
// baseline (4894.905 us; speedup 1.0000x reference)
//
#include <hip/hip_runtime.h>
#include <cstdint>
#include <cstddef>

#define NBATCH  8
#define NPTS    8192
#define NFEAT   64
#define NPOINT  2048
#define NSAMPLE 32

// ---------------------------------------------------------------------------
// prep: fold BN into weights (y = dot*s + t), transpose to [c][o]
// ---------------------------------------------------------------------------
__global__ void prep_kernel(const float* __restrict__ w1, const float* __restrict__ b1,
                            const float* __restrict__ g1, const float* __restrict__ bb1,
                            const float* __restrict__ m1, const float* __restrict__ v1,
                            const float* __restrict__ w2, const float* __restrict__ b2,
                            const float* __restrict__ g2, const float* __restrict__ bb2,
                            const float* __restrict__ m2, const float* __restrict__ v2,
                            const float* __restrict__ w3, const float* __restrict__ b3,
                            const float* __restrict__ g3, const float* __restrict__ bb3,
                            const float* __restrict__ m3, const float* __restrict__ v3,
                            float* __restrict__ wbuf) {
    int i = blockIdx.x * 256 + threadIdx.x;
    if (i < 4288) {
        int o = i & 63, c = i >> 6;
        float s = g1[o] / sqrtf(v1[o] + 1e-5f);
        wbuf[i] = w1[o * 67 + c] * s;
    } else if (i < 4352) {
        int o = i - 4288;
        float s = g1[o] / sqrtf(v1[o] + 1e-5f);
        wbuf[i] = (b1[o] - m1[o]) * s + bb1[o];
    } else if (i < 8448) {
        int j = i - 4352; int o = j & 63, c = j >> 6;
        float s = g2[o] / sqrtf(v2[o] + 1e-5f);
        wbuf[i] = w2[o * 64 + c] * s;
    } else if (i < 8512) {
        int o = i - 8448;
        float s = g2[o] / sqrtf(v2[o] + 1e-5f);
        wbuf[i] = (b2[o] - m2[o]) * s + bb2[o];
    } else if (i < 16704) {
        int j = i - 8512; int o = j & 127, c = j >> 7;
        float s = g3[o] / sqrtf(v3[o] + 1e-5f);
        wbuf[i] = w3[o * 64 + c] * s;
    } else if (i < 16832) {
        int o = i - 16704;
        float s = g3[o] / sqrtf(v3[o] + 1e-5f);
        wbuf[i] = (b3[o] - m3[o]) * s + bb3[o];
    }
}

// ---------------------------------------------------------------------------
// FPS — R3 register-resident structure (512 thr, 16 pts/thread, shfl-only)
// with a shortened post-update chain: the in-wave shfl reduce carries the
// winner's COORDINATES (take-flag from (v,o) only -> semantics identical),
// lane 0 writes a 5-value partial, ONE barrier, then all threads serially
// scan the 8 partials (pipelined LDS broadcast reads) -> next centroid
// directly. Deletes: second shfl stage, broadcast shfl, indexed LDS fetch,
// and the 96 KB coord table. Exact IEEE f32 recipe + min-index tie-breaks
// (bit-exact through R1-R10).
// ---------------------------------------------------------------------------
__global__ __launch_bounds__(512, 2) void fps_kernel(const float* __restrict__ points,
                                                     int* __restrict__ fidx) {
    const int b = blockIdx.x;
    const int tid = threadIdx.x;
    const int lane = tid & 63;
    const int wv = tid >> 6;
    const float* __restrict__ pxg = points + (size_t)b * 3 * NPTS;
    const float* __restrict__ pyg = pxg + NPTS;
    const float* __restrict__ pzg = pyg + NPTS;

    __shared__ float pvs[2][8], pxs[2][8], pys[2][8], pzs[2][8];
    __shared__ int   pis[2][8];

    float px[16], py[16], pz[16], dd[16];
#pragma unroll
    for (int j = 0; j < 16; ++j) {
        int n = tid + 512 * j;
        px[j] = pxg[n]; py[j] = pyg[n]; pz[j] = pzg[n];
        dd[j] = 1e10f;
    }
    // initial centroid = original point 0 (broadcast global load, L2-hit)
    float cx = pxg[0], cy = pyg[0], cz = pzg[0];
    if (tid == 0) fidx[b * NPOINT + 0] = 0;

    for (int i = 1; i < NPOINT; ++i) {
        // ---- 16-point register update + thread-local argmax (track bj) ----
        float bv = -1.0f; int bj = 0;
        float bx = 0.f, by = 0.f, bz = 0.f;
#pragma unroll
        for (int j = 0; j < 16; ++j) {
            float dx = __fsub_rn(px[j], cx);
            float dy = __fsub_rn(py[j], cy);
            float dz = __fsub_rn(pz[j], cz);
            float d  = __fadd_rn(__fadd_rn(__fmul_rn(dx, dx), __fmul_rn(dy, dy)),
                                 __fmul_rn(dz, dz));
            float nd = fminf(dd[j], d);
            dd[j] = nd;
            bool take = (nd > bv);   // ascending j => ascending index; tie keeps earlier
            bv = take ? nd : bv; bj = take ? j : bj;
            bx = take ? px[j] : bx; by = take ? py[j] : by; bz = take ? pz[j] : bz;
        }
        float v = bv; int o = tid + (bj << 9);
        float wx = bx, wy = by, wz = bz;
        // ---- in-wave argmax reduce, coords ride along; lane 0 = winner ----
#pragma unroll
        for (int off = 32; off >= 1; off >>= 1) {
            float ov = __shfl_down(v, off);
            int   oo = __shfl_down(o, off);
            float ox = __shfl_down(wx, off);
            float oy = __shfl_down(wy, off);
            float oz = __shfl_down(wz, off);
            bool tk = (ov > v) || (ov == v && oo < o);
            v = tk ? ov : v; o = tk ? oo : o;
            wx = tk ? ox : wx; wy = tk ? oy : wy; wz = tk ? oz : wz;
        }
        const int par = i & 1;  // parity double-buffer -> single barrier/iter
        if (lane == 0) {
            pvs[par][wv] = v; pis[par][wv] = o;
            pxs[par][wv] = wx; pys[par][wv] = wy; pzs[par][wv] = wz;
        }
        __syncthreads();
        // ---- serial scan of 8 partials (pipelined LDS broadcast reads) ----
        float M = pvs[par][0]; int I = pis[par][0];
        float nx = pxs[par][0], ny = pys[par][0], nz = pzs[par][0];
#pragma unroll
        for (int k = 1; k < 8; ++k) {
            float vk = pvs[par][k]; int ok = pis[par][k];
            bool tk = (vk > M) || (vk == M && ok < I);
            M = tk ? vk : M; I = tk ? ok : I;
            nx = tk ? pxs[par][k] : nx;
            ny = tk ? pys[par][k] : ny;
            nz = tk ? pzs[par][k] : nz;
        }
        cx = nx; cy = ny; cz = nz;
        if (tid == 0) fidx[b * NPOINT + i] = I;
    }
}

// ---------------------------------------------------------------------------
// Ball query: one wave per query. d = (qq+pp) - 2*qp, compare vs 0.04f.
// qp is the K=3 einsum/dot -> ascending FMA chain (verified exact in R1).
// ---------------------------------------------------------------------------
__global__ __launch_bounds__(256) void bq_kernel(const float* __restrict__ points,
                                                 const int* __restrict__ fidx,
                                                 int* __restrict__ ballidx,
                                                 float* __restrict__ out_xyz) {
    const int lane = threadIdx.x & 63;
    const int gw = (blockIdx.x << 2) + (threadIdx.x >> 6);
    const int b = gw >> 11;
    const int q = gw & 2047;
    const float* __restrict__ pxg = points + (size_t)b * 3 * NPTS;
    const float* __restrict__ pyg = pxg + NPTS;
    const float* __restrict__ pzg = pyg + NPTS;
    const int qi = fidx[b * NPOINT + q];
    const float qx = pxg[qi], qy = pyg[qi], qz = pzg[qi];
    const float qq = __fadd_rn(__fadd_rn(__fmul_rn(qx, qx), __fmul_rn(qy, qy)),
                               __fmul_rn(qz, qz));
    int* __restrict__ out = ballidx + ((size_t)(b * NPOINT + q)) * NSAMPLE;
    int have = 0;
    int first = -1;
    for (int base = 0; base < NPTS && have < NSAMPLE; base += 64) {
        const int n = base + lane;
        float x = pxg[n], y = pyg[n], z = pzg[n];
        float pp = __fadd_rn(__fadd_rn(__fmul_rn(x, x), __fmul_rn(y, y)), __fmul_rn(z, z));
        float qp = __builtin_fmaf(qz, z, __builtin_fmaf(qy, y, __fmul_rn(qx, x)));
        float d  = __fsub_rn(__fadd_rn(qq, pp), __fmul_rn(2.0f, qp));
        bool inb = d < 0.04f;   // f32(0.2*0.2) == 0.04f
        unsigned long long mask = __ballot(inb);
        if (mask) {
            if (first < 0) first = base + __ffsll(mask) - 1;
            if (inb) {
                int slot = have + (int)__popcll(mask & ((1ull << lane) - 1ull));
                if (slot < NSAMPLE) out[slot] = n;
            }
            have += (int)__popcll(mask);
        }
    }
    for (int s = have + lane; s < NSAMPLE; s += 64) out[s] = first;
    if (lane == 0) {
        float* o0 = out_xyz + (size_t)b * 3 * NPOINT + q;
        o0[0] = qx; o0[NPOINT] = qy; o0[2 * NPOINT] = qz;
    }
}

// ---------------------------------------------------------------------------
// Fused gather + 3-layer MLP + max-pool, TWO queries per block (k = 64).
// (R10-validated: bit-identical, ~45 us faster than 1-query version.)
// ---------------------------------------------------------------------------
#define XS2 68   // 64 + 4 pad (16B-aligned rows, 8-way-max write conflicts)
__global__ __launch_bounds__(256) void mlp_kernel(const float* __restrict__ feats,
                                                  const float* __restrict__ points,
                                                  const int* __restrict__ fidx,
                                                  const int* __restrict__ ballidx,
                                                  const float* __restrict__ wbuf,
                                                  float* __restrict__ out) {
    __shared__ __align__(16) float xT[67 * XS2];   // [c][k], reused for y2
    __shared__ __align__(16) float yA[64 * XS2];   // y1
    __shared__ __align__(16) float wl[8192];       // current layer weights [c][o]
    __shared__ float bl[128];
    __shared__ int   il[64];
    __shared__ float qv[6];
    const int tid = threadIdx.x;
    const int blk = blockIdx.x;
    const int b = blk >> 10;            // 1024 query-pairs per batch
    const int q0 = (blk & 1023) * 2;
    const float* __restrict__ pb = points + (size_t)b * 3 * NPTS;
    const float4* __restrict__ wb4 = (const float4*)wbuf;

    if (tid < 64)
        il[tid] = ballidx[((size_t)(b * NPOINT + q0 + (tid >> 5))) * NSAMPLE + (tid & 31)];
    if (tid < 6) {
        int qq_ = tid / 3, dim = tid % 3;
        qv[tid] = pb[(size_t)dim * NPTS + fidx[b * NPOINT + q0 + qq_]];
    }
    // stage layer-1 weights (4288 floats = 1072 float4)
    for (int i = tid; i < 1072; i += 256) ((float4*)wl)[i] = wb4[i];
    if (tid < 64) bl[tid] = wbuf[4288 + tid];
    __syncthreads();

    // build xT: rows 0..2 = grouped_xyz, rows 3..66 = gathered features
    if (tid < 64) {
        int n = il[tid], qsel = tid >> 5;
        xT[0 * XS2 + tid] = pb[n] - qv[qsel * 3 + 0];
        xT[1 * XS2 + tid] = pb[NPTS + n] - qv[qsel * 3 + 1];
        xT[2 * XS2 + tid] = pb[2 * NPTS + n] - qv[qsel * 3 + 2];
    }
    {
        int k = tid & 63, fg = tid >> 6;          // 4 groups x 16 feature rows
        int n = il[k];
        const float* fb = feats + ((size_t)b * NFEAT + fg * 16) * NPTS + n;
#pragma unroll
        for (int u = 0; u < 16; ++u) xT[(3 + fg * 16 + u) * XS2 + k] = fb[(size_t)u * NPTS];
    }
    __syncthreads();

    const int o = tid & 63, w = tid >> 6;   // wave w owns samples [w*16, w*16+16)
    float acc[16];
    // ---- layer 1: 67 -> 64 ----
#pragma unroll
    for (int j = 0; j < 16; ++j) acc[j] = 0.f;
    for (int c = 0; c < 67; ++c) {
        float wv = wl[c * 64 + o];
        const float4* xp = (const float4*)&xT[c * XS2 + w * 16];
        float4 a0 = xp[0], a1 = xp[1], a2 = xp[2], a3v = xp[3];
        acc[0]  = fmaf(wv, a0.x, acc[0]);  acc[1]  = fmaf(wv, a0.y, acc[1]);
        acc[2]  = fmaf(wv, a0.z, acc[2]);  acc[3]  = fmaf(wv, a0.w, acc[3]);
        acc[4]  = fmaf(wv, a1.x, acc[4]);  acc[5]  = fmaf(wv, a1.y, acc[5]);
        acc[6]  = fmaf(wv, a1.z, acc[6]);  acc[7]  = fmaf(wv, a1.w, acc[7]);
        acc[8]  = fmaf(wv, a2.x, acc[8]);  acc[9]  = fmaf(wv, a2.y, acc[9]);
        acc[10] = fmaf(wv, a2.z, acc[10]); acc[11] = fmaf(wv, a2.w, acc[11]);
        acc[12] = fmaf(wv, a3v.x, acc[12]); acc[13] = fmaf(wv, a3v.y, acc[13]);
        acc[14] = fmaf(wv, a3v.z, acc[14]); acc[15] = fmaf(wv, a3v.w, acc[15]);
    }
    {
        float t = bl[o];
#pragma unroll
        for (int j = 0; j < 16; ++j) {
            float y = acc[j] + t;
            y = y > 0.f ? y : 0.2f * y;
            yA[o * XS2 + w * 16 + j] = y;
        }
    }
    __syncthreads();
    for (int i = tid; i < 1024; i += 256) ((float4*)wl)[i] = wb4[1088 + i];
    if (tid < 64) bl[tid] = wbuf[8448 + tid];
    __syncthreads();

    // ---- layer 2: 64 -> 64 ----
#pragma unroll
    for (int j = 0; j < 16; ++j) acc[j] = 0.f;
    for (int c = 0; c < 64; ++c) {
        float wv = wl[c * 64 + o];
        const float4* xp = (const float4*)&yA[c * XS2 + w * 16];
        float4 a0 = xp[0], a1 = xp[1], a2 = xp[2], a3v = xp[3];
        acc[0]  = fmaf(wv, a0.x, acc[0]);  acc[1]  = fmaf(wv, a0.y, acc[1]);
        acc[2]  = fmaf(wv, a0.z, acc[2]);  acc[3]  = fmaf(wv, a0.w, acc[3]);
        acc[4]  = fmaf(wv, a1.x, acc[4]);  acc[5]  = fmaf(wv, a1.y, acc[5]);
        acc[6]  = fmaf(wv, a1.z, acc[6]);  acc[7]  = fmaf(wv, a1.w, acc[7]);
        acc[8]  = fmaf(wv, a2.x, acc[8]);  acc[9]  = fmaf(wv, a2.y, acc[9]);
        acc[10] = fmaf(wv, a2.z, acc[10]); acc[11] = fmaf(wv, a2.w, acc[11]);
        acc[12] = fmaf(wv, a3v.x, acc[12]); acc[13] = fmaf(wv, a3v.y, acc[13]);
        acc[14] = fmaf(wv, a3v.z, acc[14]); acc[15] = fmaf(wv, a3v.w, acc[15]);
    }
    {
        float t = bl[o];
#pragma unroll
        for (int j = 0; j < 16; ++j) {
            float y = acc[j] + t;
            y = y > 0.f ? y : 0.2f * y;
            xT[o * XS2 + w * 16 + j] = y;   // y2 into xT (xT reads all done)
        }
    }
    __syncthreads();
    for (int i = tid; i < 2048; i += 256) ((float4*)wl)[i] = wb4[2128 + i];
    if (tid < 128) bl[tid] = wbuf[16704 + tid];
    __syncthreads();

    // ---- layer 3: 64 -> 128, max over this thread's query (32 samples) ----
    const int o3 = tid & 127, kb3 = tid >> 7;   // kb3 = query select
    float a3[32];
#pragma unroll
    for (int j = 0; j < 32; ++j) a3[j] = 0.f;
    for (int c = 0; c < 64; ++c) {
        float wv = wl[c * 128 + o3];
        const float4* xp = (const float4*)&xT[c * XS2 + kb3 * 32];
#pragma unroll
        for (int g = 0; g < 8; ++g) {
            float4 x = xp[g];
            a3[g * 4 + 0] = fmaf(wv, x.x, a3[g * 4 + 0]);
            a3[g * 4 + 1] = fmaf(wv, x.y, a3[g * 4 + 1]);
            a3[g * 4 + 2] = fmaf(wv, x.z, a3[g * 4 + 2]);
            a3[g * 4 + 3] = fmaf(wv, x.w, a3[g * 4 + 3]);
        }
    }
    {
        float t = bl[o3];
        float m = -3.4e38f;
#pragma unroll
        for (int j = 0; j < 32; ++j) {
            float y = a3[j] + t;
            y = y > 0.f ? y : 0.2f * y;
            m = fmaxf(m, y);
        }
        out[((size_t)b * 128 + o3) * NPOINT + q0 + kb3] = m;
    }
}

// ---------------------------------------------------------------------------
extern "C" void kernel_launch(void* const* d_in, const int* in_sizes, int n_in,
                              void* d_out, int out_size, void* d_ws, size_t ws_size,
                              hipStream_t stream) {
    (void)in_sizes; (void)n_in; (void)out_size; (void)ws_size;
    const float* feats  = (const float*)d_in[0];
    const float* points = (const float*)d_in[1];
    const float* w1  = (const float*)d_in[2];
    const float* b1  = (const float*)d_in[3];
    const float* g1  = (const float*)d_in[4];
    const float* bb1 = (const float*)d_in[5];
    const float* m1  = (const float*)d_in[6];
    const float* v1  = (const float*)d_in[7];
    const float* w2  = (const float*)d_in[8];
    const float* b2  = (const float*)d_in[9];
    const float* g2  = (const float*)d_in[10];
    const float* bb2 = (const float*)d_in[11];
    const float* m2  = (const float*)d_in[12];
    const float* v2  = (const float*)d_in[13];
    const float* w3  = (const float*)d_in[14];
    const float* b3  = (const float*)d_in[15];
    const float* g3  = (const float*)d_in[16];
    const float* bb3 = (const float*)d_in[17];
    const float* m3  = (const float*)d_in[18];
    const float* v3  = (const float*)d_in[19];

    float* out = (float*)d_out;
    char*  ws  = (char*)d_ws;
    int*   fidx    = (int*)ws;                           // 8*2048 int = 64 KB
    int*   ballidx = (int*)(ws + 65536);                 // 8*2048*32 int = 2 MB
    float* wbuf    = (float*)(ws + 65536 + 2097152);     // 16832 floats
    float* out_xyz = out + (size_t)NBATCH * 128 * NPOINT;

    hipLaunchKernelGGL(prep_kernel, dim3(66), dim3(256), 0, stream,
                       w1, b1, g1, bb1, m1, v1, w2, b2, g2, bb2, m2, v2,
                       w3, b3, g3, bb3, m3, v3, wbuf);
    hipLaunchKernelGGL(fps_kernel, dim3(NBATCH), dim3(512), 0, stream, points, fidx);
    hipLaunchKernelGGL(bq_kernel, dim3(16384 / 4), dim3(256), 0, stream,
                       points, fidx, ballidx, out_xyz);
    hipLaunchKernelGGL(mlp_kernel, dim3(NBATCH * 1024), dim3(256), 0, stream,
                       feats, points, fidx, ballidx, wbuf, out);
}

// Round 12
// 3413.101 us; speedup vs baseline: 1.4342x; 1.4342x over previous
//
#include <hip/hip_runtime.h>
#include <cstdint>
#include <cstddef>

#define NBATCH  8
#define NPTS    8192
#define NFEAT   64
#define NPOINT  2048
#define NSAMPLE 32

// ---------------------------------------------------------------------------
// prep: fold BN into weights (y = dot*s + t), transpose to [c][o]
// ---------------------------------------------------------------------------
__global__ void prep_kernel(const float* __restrict__ w1, const float* __restrict__ b1,
                            const float* __restrict__ g1, const float* __restrict__ bb1,
                            const float* __restrict__ m1, const float* __restrict__ v1,
                            const float* __restrict__ w2, const float* __restrict__ b2,
                            const float* __restrict__ g2, const float* __restrict__ bb2,
                            const float* __restrict__ m2, const float* __restrict__ v2,
                            const float* __restrict__ w3, const float* __restrict__ b3,
                            const float* __restrict__ g3, const float* __restrict__ bb3,
                            const float* __restrict__ m3, const float* __restrict__ v3,
                            float* __restrict__ wbuf) {
    int i = blockIdx.x * 256 + threadIdx.x;
    if (i < 4288) {
        int o = i & 63, c = i >> 6;
        float s = g1[o] / sqrtf(v1[o] + 1e-5f);
        wbuf[i] = w1[o * 67 + c] * s;
    } else if (i < 4352) {
        int o = i - 4288;
        float s = g1[o] / sqrtf(v1[o] + 1e-5f);
        wbuf[i] = (b1[o] - m1[o]) * s + bb1[o];
    } else if (i < 8448) {
        int j = i - 4352; int o = j & 63, c = j >> 6;
        float s = g2[o] / sqrtf(v2[o] + 1e-5f);
        wbuf[i] = w2[o * 64 + c] * s;
    } else if (i < 8512) {
        int o = i - 8448;
        float s = g2[o] / sqrtf(v2[o] + 1e-5f);
        wbuf[i] = (b2[o] - m2[o]) * s + bb2[o];
    } else if (i < 16704) {
        int j = i - 8512; int o = j & 127, c = j >> 7;
        float s = g3[o] / sqrtf(v3[o] + 1e-5f);
        wbuf[i] = w3[o * 64 + c] * s;
    } else if (i < 16832) {
        int o = i - 16704;
        float s = g3[o] / sqrtf(v3[o] + 1e-5f);
        wbuf[i] = (b3[o] - m3[o]) * s + bb3[o];
    }
}

// ---------------------------------------------------------------------------
// FPS — literal R3 register-resident structure (512 thr, 16 pts/thread,
// VGPR=88 proven) with ONE change: the post-barrier second-stage reduce
// (lane<8 shfl chain + broadcast) is replaced by a serial scan of the 8
// (v,o) partials by every thread (pipelined LDS broadcast reads). No extra
// state is carried through the shfl butterfly (the R6-R9/R11 spill trigger).
// Exact IEEE f32 recipe + min-index tie-breaks (bit-exact R1-R11).
// ---------------------------------------------------------------------------
__global__ __launch_bounds__(512, 2) void fps_kernel(const float* __restrict__ points,
                                                     int* __restrict__ fidx) {
    const int b = blockIdx.x;
    const int tid = threadIdx.x;
    const int lane = tid & 63;
    const float* __restrict__ pxg = points + (size_t)b * 3 * NPTS;
    const float* __restrict__ pyg = pxg + NPTS;
    const float* __restrict__ pzg = pyg + NPTS;

    __shared__ float lx[NPTS];     // 32 KB
    __shared__ float ly[NPTS];     // 32 KB
    __shared__ float lz[NPTS];     // 32 KB
    __shared__ float pv[2][8];
    __shared__ int   pi[2][8];

    float px[16], py[16], pz[16], dd[16];
#pragma unroll
    for (int j = 0; j < 16; ++j) {
        int n = tid + 512 * j;
        px[j] = pxg[n]; py[j] = pyg[n]; pz[j] = pzg[n];
        lx[n] = px[j];  ly[n] = py[j];  lz[n] = pz[j];
        dd[j] = 1e10f;
    }
    if (tid == 0) fidx[b * NPOINT + 0] = 0;
    __syncthreads();
    int w = 0;
    for (int i = 1; i < NPOINT; ++i) {
        // broadcast read of current centroid from LDS (same addr all lanes)
        const float cx = lx[w], cy = ly[w], cz = lz[w];
        float bestd = -1.0f; int besti = 0;
#pragma unroll
        for (int j = 0; j < 16; ++j) {
            float dx = __fsub_rn(px[j], cx);
            float dy = __fsub_rn(py[j], cy);
            float dz = __fsub_rn(pz[j], cz);
            float d  = __fadd_rn(__fadd_rn(__fmul_rn(dx, dx), __fmul_rn(dy, dy)),
                                 __fmul_rn(dz, dz));
            float nd = fminf(dd[j], d);
            dd[j] = nd;
            bool better = (nd > bestd);   // strict > keeps smaller idx on tie
            bestd = better ? nd : bestd;
            besti = better ? (tid + 512 * j) : besti;
        }
        // wave-level argmax reduce (max dist, tie -> min idx)
#pragma unroll
        for (int off = 32; off >= 1; off >>= 1) {
            float od = __shfl_down(bestd, off);
            int   oi = __shfl_down(besti, off);
            bool take = (od > bestd) || (od == bestd && oi < besti);
            bestd = take ? od : bestd;
            besti = take ? oi : besti;
        }
        const int par = i & 1;  // double-buffered partials -> single barrier/iter
        if (lane == 0) { pv[par][tid >> 6] = bestd; pi[par][tid >> 6] = besti; }
        __syncthreads();
        // serial scan of the 8 partials by every thread (pipelined LDS reads)
        float M = pv[par][0]; int I = pi[par][0];
#pragma unroll
        for (int k = 1; k < 8; ++k) {
            float vk = pv[par][k]; int ok = pi[par][k];
            bool take = (vk > M) || (vk == M && ok < I);
            M = take ? vk : M; I = take ? ok : I;
        }
        w = I;
        if (tid == 0) fidx[b * NPOINT + i] = I;
    }
}

// ---------------------------------------------------------------------------
// Ball query: one wave per query. d = (qq+pp) - 2*qp, compare vs 0.04f.
// qp is the K=3 einsum/dot -> ascending FMA chain (verified exact in R1).
// ---------------------------------------------------------------------------
__global__ __launch_bounds__(256) void bq_kernel(const float* __restrict__ points,
                                                 const int* __restrict__ fidx,
                                                 int* __restrict__ ballidx,
                                                 float* __restrict__ out_xyz) {
    const int lane = threadIdx.x & 63;
    const int gw = (blockIdx.x << 2) + (threadIdx.x >> 6);
    const int b = gw >> 11;
    const int q = gw & 2047;
    const float* __restrict__ pxg = points + (size_t)b * 3 * NPTS;
    const float* __restrict__ pyg = pxg + NPTS;
    const float* __restrict__ pzg = pyg + NPTS;
    const int qi = fidx[b * NPOINT + q];
    const float qx = pxg[qi], qy = pyg[qi], qz = pzg[qi];
    const float qq = __fadd_rn(__fadd_rn(__fmul_rn(qx, qx), __fmul_rn(qy, qy)),
                               __fmul_rn(qz, qz));
    int* __restrict__ out = ballidx + ((size_t)(b * NPOINT + q)) * NSAMPLE;
    int have = 0;
    int first = -1;
    for (int base = 0; base < NPTS && have < NSAMPLE; base += 64) {
        const int n = base + lane;
        float x = pxg[n], y = pyg[n], z = pzg[n];
        float pp = __fadd_rn(__fadd_rn(__fmul_rn(x, x), __fmul_rn(y, y)), __fmul_rn(z, z));
        float qp = __builtin_fmaf(qz, z, __builtin_fmaf(qy, y, __fmul_rn(qx, x)));
        float d  = __fsub_rn(__fadd_rn(qq, pp), __fmul_rn(2.0f, qp));
        bool inb = d < 0.04f;   // f32(0.2*0.2) == 0.04f
        unsigned long long mask = __ballot(inb);
        if (mask) {
            if (first < 0) first = base + __ffsll(mask) - 1;
            if (inb) {
                int slot = have + (int)__popcll(mask & ((1ull << lane) - 1ull));
                if (slot < NSAMPLE) out[slot] = n;
            }
            have += (int)__popcll(mask);
        }
    }
    for (int s = have + lane; s < NSAMPLE; s += 64) out[s] = first;
    if (lane == 0) {
        float* o0 = out_xyz + (size_t)b * 3 * NPOINT + q;
        o0[0] = qx; o0[NPOINT] = qy; o0[2 * NPOINT] = qz;
    }
}

// ---------------------------------------------------------------------------
// Fused gather + 3-layer MLP + max-pool, TWO queries per block (k = 64).
// (R10-validated: bit-identical, ~45 us faster than 1-query version.)
// ---------------------------------------------------------------------------
#define XS2 68   // 64 + 4 pad (16B-aligned rows, 8-way-max write conflicts)
__global__ __launch_bounds__(256) void mlp_kernel(const float* __restrict__ feats,
                                                  const float* __restrict__ points,
                                                  const int* __restrict__ fidx,
                                                  const int* __restrict__ ballidx,
                                                  const float* __restrict__ wbuf,
                                                  float* __restrict__ out) {
    __shared__ __align__(16) float xT[67 * XS2];   // [c][k], reused for y2
    __shared__ __align__(16) float yA[64 * XS2];   // y1
    __shared__ __align__(16) float wl[8192];       // current layer weights [c][o]
    __shared__ float bl[128];
    __shared__ int   il[64];
    __shared__ float qv[6];
    const int tid = threadIdx.x;
    const int blk = blockIdx.x;
    const int b = blk >> 10;            // 1024 query-pairs per batch
    const int q0 = (blk & 1023) * 2;
    const float* __restrict__ pb = points + (size_t)b * 3 * NPTS;
    const float4* __restrict__ wb4 = (const float4*)wbuf;

    if (tid < 64)
        il[tid] = ballidx[((size_t)(b * NPOINT + q0 + (tid >> 5))) * NSAMPLE + (tid & 31)];
    if (tid < 6) {
        int qq_ = tid / 3, dim = tid % 3;
        qv[tid] = pb[(size_t)dim * NPTS + fidx[b * NPOINT + q0 + qq_]];
    }
    // stage layer-1 weights (4288 floats = 1072 float4)
    for (int i = tid; i < 1072; i += 256) ((float4*)wl)[i] = wb4[i];
    if (tid < 64) bl[tid] = wbuf[4288 + tid];
    __syncthreads();

    // build xT: rows 0..2 = grouped_xyz, rows 3..66 = gathered features
    if (tid < 64) {
        int n = il[tid], qsel = tid >> 5;
        xT[0 * XS2 + tid] = pb[n] - qv[qsel * 3 + 0];
        xT[1 * XS2 + tid] = pb[NPTS + n] - qv[qsel * 3 + 1];
        xT[2 * XS2 + tid] = pb[2 * NPTS + n] - qv[qsel * 3 + 2];
    }
    {
        int k = tid & 63, fg = tid >> 6;          // 4 groups x 16 feature rows
        int n = il[k];
        const float* fb = feats + ((size_t)b * NFEAT + fg * 16) * NPTS + n;
#pragma unroll
        for (int u = 0; u < 16; ++u) xT[(3 + fg * 16 + u) * XS2 + k] = fb[(size_t)u * NPTS];
    }
    __syncthreads();

    const int o = tid & 63, w = tid >> 6;   // wave w owns samples [w*16, w*16+16)
    float acc[16];
    // ---- layer 1: 67 -> 64 ----
#pragma unroll
    for (int j = 0; j < 16; ++j) acc[j] = 0.f;
    for (int c = 0; c < 67; ++c) {
        float wv = wl[c * 64 + o];
        const float4* xp = (const float4*)&xT[c * XS2 + w * 16];
        float4 a0 = xp[0], a1 = xp[1], a2 = xp[2], a3v = xp[3];
        acc[0]  = fmaf(wv, a0.x, acc[0]);  acc[1]  = fmaf(wv, a0.y, acc[1]);
        acc[2]  = fmaf(wv, a0.z, acc[2]);  acc[3]  = fmaf(wv, a0.w, acc[3]);
        acc[4]  = fmaf(wv, a1.x, acc[4]);  acc[5]  = fmaf(wv, a1.y, acc[5]);
        acc[6]  = fmaf(wv, a1.z, acc[6]);  acc[7]  = fmaf(wv, a1.w, acc[7]);
        acc[8]  = fmaf(wv, a2.x, acc[8]);  acc[9]  = fmaf(wv, a2.y, acc[9]);
        acc[10] = fmaf(wv, a2.z, acc[10]); acc[11] = fmaf(wv, a2.w, acc[11]);
        acc[12] = fmaf(wv, a3v.x, acc[12]); acc[13] = fmaf(wv, a3v.y, acc[13]);
        acc[14] = fmaf(wv, a3v.z, acc[14]); acc[15] = fmaf(wv, a3v.w, acc[15]);
    }
    {
        float t = bl[o];
#pragma unroll
        for (int j = 0; j < 16; ++j) {
            float y = acc[j] + t;
            y = y > 0.f ? y : 0.2f * y;
            yA[o * XS2 + w * 16 + j] = y;
        }
    }
    __syncthreads();
    for (int i = tid; i < 1024; i += 256) ((float4*)wl)[i] = wb4[1088 + i];
    if (tid < 64) bl[tid] = wbuf[8448 + tid];
    __syncthreads();

    // ---- layer 2: 64 -> 64 ----
#pragma unroll
    for (int j = 0; j < 16; ++j) acc[j] = 0.f;
    for (int c = 0; c < 64; ++c) {
        float wv = wl[c * 64 + o];
        const float4* xp = (const float4*)&yA[c * XS2 + w * 16];
        float4 a0 = xp[0], a1 = xp[1], a2 = xp[2], a3v = xp[3];
        acc[0]  = fmaf(wv, a0.x, acc[0]);  acc[1]  = fmaf(wv, a0.y, acc[1]);
        acc[2]  = fmaf(wv, a0.z, acc[2]);  acc[3]  = fmaf(wv, a0.w, acc[3]);
        acc[4]  = fmaf(wv, a1.x, acc[4]);  acc[5]  = fmaf(wv, a1.y, acc[5]);
        acc[6]  = fmaf(wv, a1.z, acc[6]);  acc[7]  = fmaf(wv, a1.w, acc[7]);
        acc[8]  = fmaf(wv, a2.x, acc[8]);  acc[9]  = fmaf(wv, a2.y, acc[9]);
        acc[10] = fmaf(wv, a2.z, acc[10]); acc[11] = fmaf(wv, a2.w, acc[11]);
        acc[12] = fmaf(wv, a3v.x, acc[12]); acc[13] = fmaf(wv, a3v.y, acc[13]);
        acc[14] = fmaf(wv, a3v.z, acc[14]); acc[15] = fmaf(wv, a3v.w, acc[15]);
    }
    {
        float t = bl[o];
#pragma unroll
        for (int j = 0; j < 16; ++j) {
            float y = acc[j] + t;
            y = y > 0.f ? y : 0.2f * y;
            xT[o * XS2 + w * 16 + j] = y;   // y2 into xT (xT reads all done)
        }
    }
    __syncthreads();
    for (int i = tid; i < 2048; i += 256) ((float4*)wl)[i] = wb4[2128 + i];
    if (tid < 128) bl[tid] = wbuf[16704 + tid];
    __syncthreads();

    // ---- layer 3: 64 -> 128, max over this thread's query (32 samples) ----
    const int o3 = tid & 127, kb3 = tid >> 7;   // kb3 = query select
    float a3[32];
#pragma unroll
    for (int j = 0; j < 32; ++j) a3[j] = 0.f;
    for (int c = 0; c < 64; ++c) {
        float wv = wl[c * 128 + o3];
        const float4* xp = (const float4*)&xT[c * XS2 + kb3 * 32];
#pragma unroll
        for (int g = 0; g < 8; ++g) {
            float4 x = xp[g];
            a3[g * 4 + 0] = fmaf(wv, x.x, a3[g * 4 + 0]);
            a3[g * 4 + 1] = fmaf(wv, x.y, a3[g * 4 + 1]);
            a3[g * 4 + 2] = fmaf(wv, x.z, a3[g * 4 + 2]);
            a3[g * 4 + 3] = fmaf(wv, x.w, a3[g * 4 + 3]);
        }
    }
    {
        float t = bl[o3];
        float m = -3.4e38f;
#pragma unroll
        for (int j = 0; j < 32; ++j) {
            float y = a3[j] + t;
            y = y > 0.f ? y : 0.2f * y;
            m = fmaxf(m, y);
        }
        out[((size_t)b * 128 + o3) * NPOINT + q0 + kb3] = m;
    }
}

// ---------------------------------------------------------------------------
extern "C" void kernel_launch(void* const* d_in, const int* in_sizes, int n_in,
                              void* d_out, int out_size, void* d_ws, size_t ws_size,
                              hipStream_t stream) {
    (void)in_sizes; (void)n_in; (void)out_size; (void)ws_size;
    const float* feats  = (const float*)d_in[0];
    const float* points = (const float*)d_in[1];
    const float* w1  = (const float*)d_in[2];
    const float* b1  = (const float*)d_in[3];
    const float* g1  = (const float*)d_in[4];
    const float* bb1 = (const float*)d_in[5];
    const float* m1  = (const float*)d_in[6];
    const float* v1  = (const float*)d_in[7];
    const float* w2  = (const float*)d_in[8];
    const float* b2  = (const float*)d_in[9];
    const float* g2  = (const float*)d_in[10];
    const float* bb2 = (const float*)d_in[11];
    const float* m2  = (const float*)d_in[12];
    const float* v2  = (const float*)d_in[13];
    const float* w3  = (const float*)d_in[14];
    const float* b3  = (const float*)d_in[15];
    const float* g3  = (const float*)d_in[16];
    const float* bb3 = (const float*)d_in[17];
    const float* m3  = (const float*)d_in[18];
    const float* v3  = (const float*)d_in[19];

    float* out = (float*)d_out;
    char*  ws  = (char*)d_ws;
    int*   fidx    = (int*)ws;                           // 8*2048 int = 64 KB
    int*   ballidx = (int*)(ws + 65536);                 // 8*2048*32 int = 2 MB
    float* wbuf    = (float*)(ws + 65536 + 2097152);     // 16832 floats
    float* out_xyz = out + (size_t)NBATCH * 128 * NPOINT;

    hipLaunchKernelGGL(prep_kernel, dim3(66), dim3(256), 0, stream,
                       w1, b1, g1, bb1, m1, v1, w2, b2, g2, bb2, m2, v2,
                       w3, b3, g3, bb3, m3, v3, wbuf);
    hipLaunchKernelGGL(fps_kernel, dim3(NBATCH), dim3(512), 0, stream, points, fidx);
    hipLaunchKernelGGL(bq_kernel, dim3(16384 / 4), dim3(256), 0, stream,
                       points, fidx, ballidx, out_xyz);
    hipLaunchKernelGGL(mlp_kernel, dim3(NBATCH * 1024), dim3(256), 0, stream,
                       feats, points, fidx, ballidx, wbuf, out);
}

// Round 13
// 3187.778 us; speedup vs baseline: 1.5355x; 1.0707x over previous
//
#include <hip/hip_runtime.h>
#include <cstdint>
#include <cstddef>

#define NBATCH  8
#define NPTS    8192
#define NFEAT   64
#define NPOINT  2048
#define NSAMPLE 32

// ---------------------------------------------------------------------------
// prep: fold BN into weights (y = dot*s + t), transpose to [c][o]
// ---------------------------------------------------------------------------
__global__ void prep_kernel(const float* __restrict__ w1, const float* __restrict__ b1,
                            const float* __restrict__ g1, const float* __restrict__ bb1,
                            const float* __restrict__ m1, const float* __restrict__ v1,
                            const float* __restrict__ w2, const float* __restrict__ b2,
                            const float* __restrict__ g2, const float* __restrict__ bb2,
                            const float* __restrict__ m2, const float* __restrict__ v2,
                            const float* __restrict__ w3, const float* __restrict__ b3,
                            const float* __restrict__ g3, const float* __restrict__ bb3,
                            const float* __restrict__ m3, const float* __restrict__ v3,
                            float* __restrict__ wbuf) {
    int i = blockIdx.x * 256 + threadIdx.x;
    if (i < 4288) {
        int o = i & 63, c = i >> 6;
        float s = g1[o] / sqrtf(v1[o] + 1e-5f);
        wbuf[i] = w1[o * 67 + c] * s;
    } else if (i < 4352) {
        int o = i - 4288;
        float s = g1[o] / sqrtf(v1[o] + 1e-5f);
        wbuf[i] = (b1[o] - m1[o]) * s + bb1[o];
    } else if (i < 8448) {
        int j = i - 4352; int o = j & 63, c = j >> 6;
        float s = g2[o] / sqrtf(v2[o] + 1e-5f);
        wbuf[i] = w2[o * 64 + c] * s;
    } else if (i < 8512) {
        int o = i - 8448;
        float s = g2[o] / sqrtf(v2[o] + 1e-5f);
        wbuf[i] = (b2[o] - m2[o]) * s + bb2[o];
    } else if (i < 16704) {
        int j = i - 8512; int o = j & 127, c = j >> 7;
        float s = g3[o] / sqrtf(v3[o] + 1e-5f);
        wbuf[i] = w3[o * 64 + c] * s;
    } else if (i < 16832) {
        int o = i - 16704;
        float s = g3[o] / sqrtf(v3[o] + 1e-5f);
        wbuf[i] = (b3[o] - m3[o]) * s + bb3[o];
    }
}

// ---------------------------------------------------------------------------
// FPS — literal R3 kernel (proven: VGPR=88, register-resident, 2766 us).
// 512 threads, 16 pts/thread in registers, LDS coord tables, two-stage shfl
// reduce. Exact IEEE f32 recipe, tie-break -> smallest index (numpy argmax).
// Latency-bound floor for this structure (12 rounds of variants all lost).
// ---------------------------------------------------------------------------
__global__ __launch_bounds__(512, 2) void fps_kernel(const float* __restrict__ points,
                                                     int* __restrict__ fidx) {
    const int b = blockIdx.x;
    const int tid = threadIdx.x;
    const int lane = tid & 63;
    const float* __restrict__ pxg = points + (size_t)b * 3 * NPTS;
    const float* __restrict__ pyg = pxg + NPTS;
    const float* __restrict__ pzg = pyg + NPTS;

    __shared__ float lx[NPTS];     // 32 KB
    __shared__ float ly[NPTS];     // 32 KB
    __shared__ float lz[NPTS];     // 32 KB
    __shared__ float pv[2][8];
    __shared__ int   pi[2][8];

    float px[16], py[16], pz[16], dd[16];
#pragma unroll
    for (int j = 0; j < 16; ++j) {
        int n = tid + 512 * j;
        px[j] = pxg[n]; py[j] = pyg[n]; pz[j] = pzg[n];
        lx[n] = px[j];  ly[n] = py[j];  lz[n] = pz[j];
        dd[j] = 1e10f;
    }
    if (tid == 0) fidx[b * NPOINT + 0] = 0;
    __syncthreads();
    int w = 0;
    for (int i = 1; i < NPOINT; ++i) {
        // broadcast read of current centroid from LDS (same addr all lanes)
        const float cx = lx[w], cy = ly[w], cz = lz[w];
        float bestd = -1.0f; int besti = 0;
#pragma unroll
        for (int j = 0; j < 16; ++j) {
            float dx = __fsub_rn(px[j], cx);
            float dy = __fsub_rn(py[j], cy);
            float dz = __fsub_rn(pz[j], cz);
            float d  = __fadd_rn(__fadd_rn(__fmul_rn(dx, dx), __fmul_rn(dy, dy)),
                                 __fmul_rn(dz, dz));
            float nd = fminf(dd[j], d);
            dd[j] = nd;
            bool better = (nd > bestd);   // strict > keeps smaller idx on tie
            bestd = better ? nd : bestd;
            besti = better ? (tid + 512 * j) : besti;
        }
        // wave-level argmax reduce (max dist, tie -> min idx)
#pragma unroll
        for (int off = 32; off >= 1; off >>= 1) {
            float od = __shfl_down(bestd, off);
            int   oi = __shfl_down(besti, off);
            bool take = (od > bestd) || (od == bestd && oi < besti);
            bestd = take ? od : bestd;
            besti = take ? oi : besti;
        }
        const int par = i & 1;  // double-buffered partials -> single barrier/iter
        if (lane == 0) { pv[par][tid >> 6] = bestd; pi[par][tid >> 6] = besti; }
        __syncthreads();
        // every wave redundantly reduces the 8 partials (no broadcast barrier)
        float fd = (lane < 8) ? pv[par][lane] : -1.0f;
        int   fi = (lane < 8) ? pi[par][lane] : 0x7fffffff;
#pragma unroll
        for (int off = 4; off >= 1; off >>= 1) {
            float od = __shfl_down(fd, off);
            int   oi = __shfl_down(fi, off);
            bool take = (od > fd) || (od == fd && oi < fi);
            fd = take ? od : fd;
            fi = take ? oi : fi;
        }
        w = __shfl(fi, 0);
        if (tid == 0) fidx[b * NPOINT + i] = w;
    }
}

// ---------------------------------------------------------------------------
// Ball query: one wave per query. d = (qq+pp) - 2*qp, compare vs 0.04f.
// qp is the K=3 einsum/dot -> ascending FMA chain (verified exact in R1).
// ---------------------------------------------------------------------------
__global__ __launch_bounds__(256) void bq_kernel(const float* __restrict__ points,
                                                 const int* __restrict__ fidx,
                                                 int* __restrict__ ballidx,
                                                 float* __restrict__ out_xyz) {
    const int lane = threadIdx.x & 63;
    const int gw = (blockIdx.x << 2) + (threadIdx.x >> 6);
    const int b = gw >> 11;
    const int q = gw & 2047;
    const float* __restrict__ pxg = points + (size_t)b * 3 * NPTS;
    const float* __restrict__ pyg = pxg + NPTS;
    const float* __restrict__ pzg = pyg + NPTS;
    const int qi = fidx[b * NPOINT + q];
    const float qx = pxg[qi], qy = pyg[qi], qz = pzg[qi];
    const float qq = __fadd_rn(__fadd_rn(__fmul_rn(qx, qx), __fmul_rn(qy, qy)),
                               __fmul_rn(qz, qz));
    int* __restrict__ out = ballidx + ((size_t)(b * NPOINT + q)) * NSAMPLE;
    int have = 0;
    int first = -1;
    for (int base = 0; base < NPTS && have < NSAMPLE; base += 64) {
        const int n = base + lane;
        float x = pxg[n], y = pyg[n], z = pzg[n];
        float pp = __fadd_rn(__fadd_rn(__fmul_rn(x, x), __fmul_rn(y, y)), __fmul_rn(z, z));
        float qp = __builtin_fmaf(qz, z, __builtin_fmaf(qy, y, __fmul_rn(qx, x)));
        float d  = __fsub_rn(__fadd_rn(qq, pp), __fmul_rn(2.0f, qp));
        bool inb = d < 0.04f;   // f32(0.2*0.2) == 0.04f
        unsigned long long mask = __ballot(inb);
        if (mask) {
            if (first < 0) first = base + __ffsll(mask) - 1;
            if (inb) {
                int slot = have + (int)__popcll(mask & ((1ull << lane) - 1ull));
                if (slot < NSAMPLE) out[slot] = n;
            }
            have += (int)__popcll(mask);
        }
    }
    for (int s = have + lane; s < NSAMPLE; s += 64) out[s] = first;
    if (lane == 0) {
        float* o0 = out_xyz + (size_t)b * 3 * NPOINT + q;
        o0[0] = qx; o0[NPOINT] = qy; o0[2 * NPOINT] = qz;
    }
}

// ---------------------------------------------------------------------------
// Fused gather + 3-layer MLP + max-pool, TWO queries per block (k = 64).
// Layers 1/2 use a 2-output x 8-sample register tile: per c, one float2
// weight read (8B) + two b128 xT reads (32B, wave-broadcast across 32 lanes,
// reused by both outputs) -> 40B LDS per 16 FMA vs 68B before. Per-output
// FMA chain remains ascending-c fmaf -> bit-identical results.
// ---------------------------------------------------------------------------
#define XS2 68   // 64 + 4 pad (16B-aligned rows)
__global__ __launch_bounds__(256) void mlp_kernel(const float* __restrict__ feats,
                                                  const float* __restrict__ points,
                                                  const int* __restrict__ fidx,
                                                  const int* __restrict__ ballidx,
                                                  const float* __restrict__ wbuf,
                                                  float* __restrict__ out) {
    __shared__ __align__(16) float xT[67 * XS2];   // [c][k], reused for y2
    __shared__ __align__(16) float yA[64 * XS2];   // y1
    __shared__ __align__(16) float wl[8192];       // current layer weights [c][o]
    __shared__ float bl[128];
    __shared__ int   il[64];
    __shared__ float qv[6];
    const int tid = threadIdx.x;
    const int blk = blockIdx.x;
    const int b = blk >> 10;            // 1024 query-pairs per batch
    const int q0 = (blk & 1023) * 2;
    const float* __restrict__ pb = points + (size_t)b * 3 * NPTS;
    const float4* __restrict__ wb4 = (const float4*)wbuf;

    if (tid < 64)
        il[tid] = ballidx[((size_t)(b * NPOINT + q0 + (tid >> 5))) * NSAMPLE + (tid & 31)];
    if (tid < 6) {
        int qq_ = tid / 3, dim = tid % 3;
        qv[tid] = pb[(size_t)dim * NPTS + fidx[b * NPOINT + q0 + qq_]];
    }
    // stage layer-1 weights (4288 floats = 1072 float4)
    for (int i = tid; i < 1072; i += 256) ((float4*)wl)[i] = wb4[i];
    if (tid < 64) bl[tid] = wbuf[4288 + tid];
    __syncthreads();

    // build xT: rows 0..2 = grouped_xyz, rows 3..66 = gathered features
    if (tid < 64) {
        int n = il[tid], qsel = tid >> 5;
        xT[0 * XS2 + tid] = pb[n] - qv[qsel * 3 + 0];
        xT[1 * XS2 + tid] = pb[NPTS + n] - qv[qsel * 3 + 1];
        xT[2 * XS2 + tid] = pb[2 * NPTS + n] - qv[qsel * 3 + 2];
    }
    {
        int k = tid & 63, fg = tid >> 6;          // 4 groups x 16 feature rows
        int n = il[k];
        const float* fb = feats + ((size_t)b * NFEAT + fg * 16) * NPTS + n;
#pragma unroll
        for (int u = 0; u < 16; ++u) xT[(3 + fg * 16 + u) * XS2 + k] = fb[(size_t)u * NPTS];
    }
    __syncthreads();

    const int op = (tid & 31) * 2;    // output pair {op, op+1}
    const int sg = tid >> 5;          // sample group (0..7), 8 samples each
    float acc0[8], acc1[8];
    // ---- layer 1: 67 -> 64 (2-output x 8-sample register tile) ----
#pragma unroll
    for (int j = 0; j < 8; ++j) { acc0[j] = 0.f; acc1[j] = 0.f; }
    for (int c = 0; c < 67; ++c) {
        float2 wv2 = *(const float2*)&wl[c * 64 + op];
        const float4* xp = (const float4*)&xT[c * XS2 + sg * 8];
        float4 a0 = xp[0], a1 = xp[1];
        acc0[0] = fmaf(wv2.x, a0.x, acc0[0]); acc0[1] = fmaf(wv2.x, a0.y, acc0[1]);
        acc0[2] = fmaf(wv2.x, a0.z, acc0[2]); acc0[3] = fmaf(wv2.x, a0.w, acc0[3]);
        acc0[4] = fmaf(wv2.x, a1.x, acc0[4]); acc0[5] = fmaf(wv2.x, a1.y, acc0[5]);
        acc0[6] = fmaf(wv2.x, a1.z, acc0[6]); acc0[7] = fmaf(wv2.x, a1.w, acc0[7]);
        acc1[0] = fmaf(wv2.y, a0.x, acc1[0]); acc1[1] = fmaf(wv2.y, a0.y, acc1[1]);
        acc1[2] = fmaf(wv2.y, a0.z, acc1[2]); acc1[3] = fmaf(wv2.y, a0.w, acc1[3]);
        acc1[4] = fmaf(wv2.y, a1.x, acc1[4]); acc1[5] = fmaf(wv2.y, a1.y, acc1[5]);
        acc1[6] = fmaf(wv2.y, a1.z, acc1[6]); acc1[7] = fmaf(wv2.y, a1.w, acc1[7]);
    }
    {
        float t0 = bl[op], t1 = bl[op + 1];
#pragma unroll
        for (int j = 0; j < 8; ++j) {
            float y0 = acc0[j] + t0;
            y0 = y0 > 0.f ? y0 : 0.2f * y0;
            yA[op * XS2 + sg * 8 + j] = y0;
            float y1 = acc1[j] + t1;
            y1 = y1 > 0.f ? y1 : 0.2f * y1;
            yA[(op + 1) * XS2 + sg * 8 + j] = y1;
        }
    }
    __syncthreads();
    for (int i = tid; i < 1024; i += 256) ((float4*)wl)[i] = wb4[1088 + i];
    if (tid < 64) bl[tid] = wbuf[8448 + tid];
    __syncthreads();

    // ---- layer 2: 64 -> 64 (same 2x8 tile) ----
#pragma unroll
    for (int j = 0; j < 8; ++j) { acc0[j] = 0.f; acc1[j] = 0.f; }
    for (int c = 0; c < 64; ++c) {
        float2 wv2 = *(const float2*)&wl[c * 64 + op];
        const float4* xp = (const float4*)&yA[c * XS2 + sg * 8];
        float4 a0 = xp[0], a1 = xp[1];
        acc0[0] = fmaf(wv2.x, a0.x, acc0[0]); acc0[1] = fmaf(wv2.x, a0.y, acc0[1]);
        acc0[2] = fmaf(wv2.x, a0.z, acc0[2]); acc0[3] = fmaf(wv2.x, a0.w, acc0[3]);
        acc0[4] = fmaf(wv2.x, a1.x, acc0[4]); acc0[5] = fmaf(wv2.x, a1.y, acc0[5]);
        acc0[6] = fmaf(wv2.x, a1.z, acc0[6]); acc0[7] = fmaf(wv2.x, a1.w, acc0[7]);
        acc1[0] = fmaf(wv2.y, a0.x, acc1[0]); acc1[1] = fmaf(wv2.y, a0.y, acc1[1]);
        acc1[2] = fmaf(wv2.y, a0.z, acc1[2]); acc1[3] = fmaf(wv2.y, a0.w, acc1[3]);
        acc1[4] = fmaf(wv2.y, a1.x, acc1[4]); acc1[5] = fmaf(wv2.y, a1.y, acc1[5]);
        acc1[6] = fmaf(wv2.y, a1.z, acc1[6]); acc1[7] = fmaf(wv2.y, a1.w, acc1[7]);
    }
    {
        float t0 = bl[op], t1 = bl[op + 1];
#pragma unroll
        for (int j = 0; j < 8; ++j) {
            float y0 = acc0[j] + t0;
            y0 = y0 > 0.f ? y0 : 0.2f * y0;
            xT[op * XS2 + sg * 8 + j] = y0;     // y2 into xT (reads all done)
            float y1 = acc1[j] + t1;
            y1 = y1 > 0.f ? y1 : 0.2f * y1;
            xT[(op + 1) * XS2 + sg * 8 + j] = y1;
        }
    }
    __syncthreads();
    for (int i = tid; i < 2048; i += 256) ((float4*)wl)[i] = wb4[2128 + i];
    if (tid < 128) bl[tid] = wbuf[16704 + tid];
    __syncthreads();

    // ---- layer 3: 64 -> 128, max over this thread's query (32 samples) ----
    const int o3 = tid & 127, kb3 = tid >> 7;   // kb3 = query select
    float a3[32];
#pragma unroll
    for (int j = 0; j < 32; ++j) a3[j] = 0.f;
    for (int c = 0; c < 64; ++c) {
        float wv = wl[c * 128 + o3];
        const float4* xp = (const float4*)&xT[c * XS2 + kb3 * 32];
#pragma unroll
        for (int g = 0; g < 8; ++g) {
            float4 x = xp[g];
            a3[g * 4 + 0] = fmaf(wv, x.x, a3[g * 4 + 0]);
            a3[g * 4 + 1] = fmaf(wv, x.y, a3[g * 4 + 1]);
            a3[g * 4 + 2] = fmaf(wv, x.z, a3[g * 4 + 2]);
            a3[g * 4 + 3] = fmaf(wv, x.w, a3[g * 4 + 3]);
        }
    }
    {
        float t = bl[o3];
        float m = -3.4e38f;
#pragma unroll
        for (int j = 0; j < 32; ++j) {
            float y = a3[j] + t;
            y = y > 0.f ? y : 0.2f * y;
            m = fmaxf(m, y);
        }
        out[((size_t)b * 128 + o3) * NPOINT + q0 + kb3] = m;
    }
}

// ---------------------------------------------------------------------------
extern "C" void kernel_launch(void* const* d_in, const int* in_sizes, int n_in,
                              void* d_out, int out_size, void* d_ws, size_t ws_size,
                              hipStream_t stream) {
    (void)in_sizes; (void)n_in; (void)out_size; (void)ws_size;
    const float* feats  = (const float*)d_in[0];
    const float* points = (const float*)d_in[1];
    const float* w1  = (const float*)d_in[2];
    const float* b1  = (const float*)d_in[3];
    const float* g1  = (const float*)d_in[4];
    const float* bb1 = (const float*)d_in[5];
    const float* m1  = (const float*)d_in[6];
    const float* v1  = (const float*)d_in[7];
    const float* w2  = (const float*)d_in[8];
    const float* b2  = (const float*)d_in[9];
    const float* g2  = (const float*)d_in[10];
    const float* bb2 = (const float*)d_in[11];
    const float* m2  = (const float*)d_in[12];
    const float* v2  = (const float*)d_in[13];
    const float* w3  = (const float*)d_in[14];
    const float* b3  = (const float*)d_in[15];
    const float* g3  = (const float*)d_in[16];
    const float* bb3 = (const float*)d_in[17];
    const float* m3  = (const float*)d_in[18];
    const float* v3  = (const float*)d_in[19];

    float* out = (float*)d_out;
    char*  ws  = (char*)d_ws;
    int*   fidx    = (int*)ws;                           // 8*2048 int = 64 KB
    int*   ballidx = (int*)(ws + 65536);                 // 8*2048*32 int = 2 MB
    float* wbuf    = (float*)(ws + 65536 + 2097152);     // 16832 floats
    float* out_xyz = out + (size_t)NBATCH * 128 * NPOINT;

    hipLaunchKernelGGL(prep_kernel, dim3(66), dim3(256), 0, stream,
                       w1, b1, g1, bb1, m1, v1, w2, b2, g2, bb2, m2, v2,
                       w3, b3, g3, bb3, m3, v3, wbuf);
    hipLaunchKernelGGL(fps_kernel, dim3(NBATCH), dim3(512), 0, stream, points, fidx);
    hipLaunchKernelGGL(bq_kernel, dim3(16384 / 4), dim3(256), 0, stream,
                       points, fidx, ballidx, out_xyz);
    hipLaunchKernelGGL(mlp_kernel, dim3(NBATCH * 1024), dim3(256), 0, stream,
                       feats, points, fidx, ballidx, wbuf, out);
}

// Round 14
// 3061.710 us; speedup vs baseline: 1.5987x; 1.0412x over previous
//
#include <hip/hip_runtime.h>
#include <cstdint>
#include <cstddef>

#define NBATCH  8
#define NPTS    8192
#define NFEAT   64
#define NPOINT  2048
#define NSAMPLE 32

// ---------------------------------------------------------------------------
// prep: fold BN into weights (y = dot*s + t), transpose to [c][o]
// ---------------------------------------------------------------------------
__global__ void prep_kernel(const float* __restrict__ w1, const float* __restrict__ b1,
                            const float* __restrict__ g1, const float* __restrict__ bb1,
                            const float* __restrict__ m1, const float* __restrict__ v1,
                            const float* __restrict__ w2, const float* __restrict__ b2,
                            const float* __restrict__ g2, const float* __restrict__ bb2,
                            const float* __restrict__ m2, const float* __restrict__ v2,
                            const float* __restrict__ w3, const float* __restrict__ b3,
                            const float* __restrict__ g3, const float* __restrict__ bb3,
                            const float* __restrict__ m3, const float* __restrict__ v3,
                            float* __restrict__ wbuf) {
    int i = blockIdx.x * 256 + threadIdx.x;
    if (i < 4288) {
        int o = i & 63, c = i >> 6;
        float s = g1[o] / sqrtf(v1[o] + 1e-5f);
        wbuf[i] = w1[o * 67 + c] * s;
    } else if (i < 4352) {
        int o = i - 4288;
        float s = g1[o] / sqrtf(v1[o] + 1e-5f);
        wbuf[i] = (b1[o] - m1[o]) * s + bb1[o];
    } else if (i < 8448) {
        int j = i - 4352; int o = j & 63, c = j >> 6;
        float s = g2[o] / sqrtf(v2[o] + 1e-5f);
        wbuf[i] = w2[o * 64 + c] * s;
    } else if (i < 8512) {
        int o = i - 8448;
        float s = g2[o] / sqrtf(v2[o] + 1e-5f);
        wbuf[i] = (b2[o] - m2[o]) * s + bb2[o];
    } else if (i < 16704) {
        int j = i - 8512; int o = j & 127, c = j >> 7;
        float s = g3[o] / sqrtf(v3[o] + 1e-5f);
        wbuf[i] = w3[o * 64 + c] * s;
    } else if (i < 16832) {
        int o = i - 16704;
        float s = g3[o] / sqrtf(v3[o] + 1e-5f);
        wbuf[i] = (b3[o] - m3[o]) * s + bb3[o];
    }
}

// ---------------------------------------------------------------------------
// FPS — R3 register-resident structure (VGPR=88 proven). One change vs R13:
// second-stage reduce is a 3-step shfl_xor butterfly over pv[lane&7]
// (every lane ends with the winner -> no broadcast shfl, no lane<8 mask).
// Only (v,o) flows through the butterfly (proven-safe envelope).
// Exact IEEE f32 recipe + min-index tie-breaks (bit-exact R1-R13).
// ---------------------------------------------------------------------------
__global__ __launch_bounds__(512, 2) void fps_kernel(const float* __restrict__ points,
                                                     int* __restrict__ fidx) {
    const int b = blockIdx.x;
    const int tid = threadIdx.x;
    const int lane = tid & 63;
    const float* __restrict__ pxg = points + (size_t)b * 3 * NPTS;
    const float* __restrict__ pyg = pxg + NPTS;
    const float* __restrict__ pzg = pyg + NPTS;

    __shared__ float lx[NPTS];     // 32 KB
    __shared__ float ly[NPTS];     // 32 KB
    __shared__ float lz[NPTS];     // 32 KB
    __shared__ float pv[2][8];
    __shared__ int   pi[2][8];

    float px[16], py[16], pz[16], dd[16];
#pragma unroll
    for (int j = 0; j < 16; ++j) {
        int n = tid + 512 * j;
        px[j] = pxg[n]; py[j] = pyg[n]; pz[j] = pzg[n];
        lx[n] = px[j];  ly[n] = py[j];  lz[n] = pz[j];
        dd[j] = 1e10f;
    }
    if (tid == 0) fidx[b * NPOINT + 0] = 0;
    __syncthreads();
    int w = 0;
    for (int i = 1; i < NPOINT; ++i) {
        // broadcast read of current centroid from LDS (same addr all lanes)
        const float cx = lx[w], cy = ly[w], cz = lz[w];
        float bestd = -1.0f; int besti = 0;
#pragma unroll
        for (int j = 0; j < 16; ++j) {
            float dx = __fsub_rn(px[j], cx);
            float dy = __fsub_rn(py[j], cy);
            float dz = __fsub_rn(pz[j], cz);
            float d  = __fadd_rn(__fadd_rn(__fmul_rn(dx, dx), __fmul_rn(dy, dy)),
                                 __fmul_rn(dz, dz));
            float nd = fminf(dd[j], d);
            dd[j] = nd;
            bool better = (nd > bestd);   // strict > keeps smaller idx on tie
            bestd = better ? nd : bestd;
            besti = better ? (tid + 512 * j) : besti;
        }
        // wave-level argmax reduce (max dist, tie -> min idx)
#pragma unroll
        for (int off = 32; off >= 1; off >>= 1) {
            float od = __shfl_down(bestd, off);
            int   oi = __shfl_down(besti, off);
            bool take = (od > bestd) || (od == bestd && oi < besti);
            bestd = take ? od : bestd;
            besti = take ? oi : besti;
        }
        const int par = i & 1;  // double-buffered partials -> single barrier/iter
        if (lane == 0) { pv[par][tid >> 6] = bestd; pi[par][tid >> 6] = besti; }
        __syncthreads();
        // second stage: butterfly over 8 partials; every lane ends w/ winner
        float fd = pv[par][lane & 7];
        int   fi = pi[par][lane & 7];
#pragma unroll
        for (int off = 4; off >= 1; off >>= 1) {
            float od = __shfl_xor(fd, off);
            int   oi = __shfl_xor(fi, off);
            bool take = (od > fd) || (od == fd && oi < fi);
            fd = take ? od : fd;
            fi = take ? oi : fi;
        }
        w = fi;   // uniform across the wave (each 8-lane group reduced same 8)
        if (tid == 0) fidx[b * NPOINT + i] = w;
    }
}

// ---------------------------------------------------------------------------
// Ball query: one wave per query. d = (qq+pp) - 2*qp, compare vs 0.04f.
// qp is the K=3 einsum/dot -> ascending FMA chain (verified exact in R1).
// ---------------------------------------------------------------------------
__global__ __launch_bounds__(256) void bq_kernel(const float* __restrict__ points,
                                                 const int* __restrict__ fidx,
                                                 int* __restrict__ ballidx,
                                                 float* __restrict__ out_xyz) {
    const int lane = threadIdx.x & 63;
    const int gw = (blockIdx.x << 2) + (threadIdx.x >> 6);
    const int b = gw >> 11;
    const int q = gw & 2047;
    const float* __restrict__ pxg = points + (size_t)b * 3 * NPTS;
    const float* __restrict__ pyg = pxg + NPTS;
    const float* __restrict__ pzg = pyg + NPTS;
    const int qi = fidx[b * NPOINT + q];
    const float qx = pxg[qi], qy = pyg[qi], qz = pzg[qi];
    const float qq = __fadd_rn(__fadd_rn(__fmul_rn(qx, qx), __fmul_rn(qy, qy)),
                               __fmul_rn(qz, qz));
    int* __restrict__ out = ballidx + ((size_t)(b * NPOINT + q)) * NSAMPLE;
    int have = 0;
    int first = -1;
    for (int base = 0; base < NPTS && have < NSAMPLE; base += 64) {
        const int n = base + lane;
        float x = pxg[n], y = pyg[n], z = pzg[n];
        float pp = __fadd_rn(__fadd_rn(__fmul_rn(x, x), __fmul_rn(y, y)), __fmul_rn(z, z));
        float qp = __builtin_fmaf(qz, z, __builtin_fmaf(qy, y, __fmul_rn(qx, x)));
        float d  = __fsub_rn(__fadd_rn(qq, pp), __fmul_rn(2.0f, qp));
        bool inb = d < 0.04f;   // f32(0.2*0.2) == 0.04f
        unsigned long long mask = __ballot(inb);
        if (mask) {
            if (first < 0) first = base + __ffsll(mask) - 1;
            if (inb) {
                int slot = have + (int)__popcll(mask & ((1ull << lane) - 1ull));
                if (slot < NSAMPLE) out[slot] = n;
            }
            have += (int)__popcll(mask);
        }
    }
    for (int s = have + lane; s < NSAMPLE; s += 64) out[s] = first;
    if (lane == 0) {
        float* o0 = out_xyz + (size_t)b * 3 * NPOINT + q;
        o0[0] = qx; o0[NPOINT] = qy; o0[2 * NPOINT] = qz;
    }
}

// ---------------------------------------------------------------------------
// Fused gather + 3-layer MLP + max-pool, TWO queries per block (k = 64).
// Layers 1/2: 2-output x 8-sample register tile (R13-validated, bit-exact).
// ---------------------------------------------------------------------------
#define XS2 68   // 64 + 4 pad (16B-aligned rows)
__global__ __launch_bounds__(256) void mlp_kernel(const float* __restrict__ feats,
                                                  const float* __restrict__ points,
                                                  const int* __restrict__ fidx,
                                                  const int* __restrict__ ballidx,
                                                  const float* __restrict__ wbuf,
                                                  float* __restrict__ out) {
    __shared__ __align__(16) float xT[67 * XS2];   // [c][k], reused for y2
    __shared__ __align__(16) float yA[64 * XS2];   // y1
    __shared__ __align__(16) float wl[8192];       // current layer weights [c][o]
    __shared__ float bl[128];
    __shared__ int   il[64];
    __shared__ float qv[6];
    const int tid = threadIdx.x;
    const int blk = blockIdx.x;
    const int b = blk >> 10;            // 1024 query-pairs per batch
    const int q0 = (blk & 1023) * 2;
    const float* __restrict__ pb = points + (size_t)b * 3 * NPTS;
    const float4* __restrict__ wb4 = (const float4*)wbuf;

    if (tid < 64)
        il[tid] = ballidx[((size_t)(b * NPOINT + q0 + (tid >> 5))) * NSAMPLE + (tid & 31)];
    if (tid < 6) {
        int qq_ = tid / 3, dim = tid % 3;
        qv[tid] = pb[(size_t)dim * NPTS + fidx[b * NPOINT + q0 + qq_]];
    }
    // stage layer-1 weights (4288 floats = 1072 float4)
    for (int i = tid; i < 1072; i += 256) ((float4*)wl)[i] = wb4[i];
    if (tid < 64) bl[tid] = wbuf[4288 + tid];
    __syncthreads();

    // build xT: rows 0..2 = grouped_xyz, rows 3..66 = gathered features
    if (tid < 64) {
        int n = il[tid], qsel = tid >> 5;
        xT[0 * XS2 + tid] = pb[n] - qv[qsel * 3 + 0];
        xT[1 * XS2 + tid] = pb[NPTS + n] - qv[qsel * 3 + 1];
        xT[2 * XS2 + tid] = pb[2 * NPTS + n] - qv[qsel * 3 + 2];
    }
    {
        int k = tid & 63, fg = tid >> 6;          // 4 groups x 16 feature rows
        int n = il[k];
        const float* fb = feats + ((size_t)b * NFEAT + fg * 16) * NPTS + n;
#pragma unroll
        for (int u = 0; u < 16; ++u) xT[(3 + fg * 16 + u) * XS2 + k] = fb[(size_t)u * NPTS];
    }
    __syncthreads();

    const int op = (tid & 31) * 2;    // output pair {op, op+1}
    const int sg = tid >> 5;          // sample group (0..7), 8 samples each
    float acc0[8], acc1[8];
    // ---- layer 1: 67 -> 64 (2-output x 8-sample register tile) ----
#pragma unroll
    for (int j = 0; j < 8; ++j) { acc0[j] = 0.f; acc1[j] = 0.f; }
    for (int c = 0; c < 67; ++c) {
        float2 wv2 = *(const float2*)&wl[c * 64 + op];
        const float4* xp = (const float4*)&xT[c * XS2 + sg * 8];
        float4 a0 = xp[0], a1 = xp[1];
        acc0[0] = fmaf(wv2.x, a0.x, acc0[0]); acc0[1] = fmaf(wv2.x, a0.y, acc0[1]);
        acc0[2] = fmaf(wv2.x, a0.z, acc0[2]); acc0[3] = fmaf(wv2.x, a0.w, acc0[3]);
        acc0[4] = fmaf(wv2.x, a1.x, acc0[4]); acc0[5] = fmaf(wv2.x, a1.y, acc0[5]);
        acc0[6] = fmaf(wv2.x, a1.z, acc0[6]); acc0[7] = fmaf(wv2.x, a1.w, acc0[7]);
        acc1[0] = fmaf(wv2.y, a0.x, acc1[0]); acc1[1] = fmaf(wv2.y, a0.y, acc1[1]);
        acc1[2] = fmaf(wv2.y, a0.z, acc1[2]); acc1[3] = fmaf(wv2.y, a0.w, acc1[3]);
        acc1[4] = fmaf(wv2.y, a1.x, acc1[4]); acc1[5] = fmaf(wv2.y, a1.y, acc1[5]);
        acc1[6] = fmaf(wv2.y, a1.z, acc1[6]); acc1[7] = fmaf(wv2.y, a1.w, acc1[7]);
    }
    {
        float t0 = bl[op], t1 = bl[op + 1];
#pragma unroll
        for (int j = 0; j < 8; ++j) {
            float y0 = acc0[j] + t0;
            y0 = y0 > 0.f ? y0 : 0.2f * y0;
            yA[op * XS2 + sg * 8 + j] = y0;
            float y1 = acc1[j] + t1;
            y1 = y1 > 0.f ? y1 : 0.2f * y1;
            yA[(op + 1) * XS2 + sg * 8 + j] = y1;
        }
    }
    __syncthreads();
    for (int i = tid; i < 1024; i += 256) ((float4*)wl)[i] = wb4[1088 + i];
    if (tid < 64) bl[tid] = wbuf[8448 + tid];
    __syncthreads();

    // ---- layer 2: 64 -> 64 (same 2x8 tile) ----
#pragma unroll
    for (int j = 0; j < 8; ++j) { acc0[j] = 0.f; acc1[j] = 0.f; }
    for (int c = 0; c < 64; ++c) {
        float2 wv2 = *(const float2*)&wl[c * 64 + op];
        const float4* xp = (const float4*)&yA[c * XS2 + sg * 8];
        float4 a0 = xp[0], a1 = xp[1];
        acc0[0] = fmaf(wv2.x, a0.x, acc0[0]); acc0[1] = fmaf(wv2.x, a0.y, acc0[1]);
        acc0[2] = fmaf(wv2.x, a0.z, acc0[2]); acc0[3] = fmaf(wv2.x, a0.w, acc0[3]);
        acc0[4] = fmaf(wv2.x, a1.x, acc0[4]); acc0[5] = fmaf(wv2.x, a1.y, acc0[5]);
        acc0[6] = fmaf(wv2.x, a1.z, acc0[6]); acc0[7] = fmaf(wv2.x, a1.w, acc0[7]);
        acc1[0] = fmaf(wv2.y, a0.x, acc1[0]); acc1[1] = fmaf(wv2.y, a0.y, acc1[1]);
        acc1[2] = fmaf(wv2.y, a0.z, acc1[2]); acc1[3] = fmaf(wv2.y, a0.w, acc1[3]);
        acc1[4] = fmaf(wv2.y, a1.x, acc1[4]); acc1[5] = fmaf(wv2.y, a1.y, acc1[5]);
        acc1[6] = fmaf(wv2.y, a1.z, acc1[6]); acc1[7] = fmaf(wv2.y, a1.w, acc1[7]);
    }
    {
        float t0 = bl[op], t1 = bl[op + 1];
#pragma unroll
        for (int j = 0; j < 8; ++j) {
            float y0 = acc0[j] + t0;
            y0 = y0 > 0.f ? y0 : 0.2f * y0;
            xT[op * XS2 + sg * 8 + j] = y0;     // y2 into xT (reads all done)
            float y1 = acc1[j] + t1;
            y1 = y1 > 0.f ? y1 : 0.2f * y1;
            xT[(op + 1) * XS2 + sg * 8 + j] = y1;
        }
    }
    __syncthreads();
    for (int i = tid; i < 2048; i += 256) ((float4*)wl)[i] = wb4[2128 + i];
    if (tid < 128) bl[tid] = wbuf[16704 + tid];
    __syncthreads();

    // ---- layer 3: 64 -> 128, max over this thread's query (32 samples) ----
    const int o3 = tid & 127, kb3 = tid >> 7;   // kb3 = query select
    float a3[32];
#pragma unroll
    for (int j = 0; j < 32; ++j) a3[j] = 0.f;
    for (int c = 0; c < 64; ++c) {
        float wv = wl[c * 128 + o3];
        const float4* xp = (const float4*)&xT[c * XS2 + kb3 * 32];
#pragma unroll
        for (int g = 0; g < 8; ++g) {
            float4 x = xp[g];
            a3[g * 4 + 0] = fmaf(wv, x.x, a3[g * 4 + 0]);
            a3[g * 4 + 1] = fmaf(wv, x.y, a3[g * 4 + 1]);
            a3[g * 4 + 2] = fmaf(wv, x.z, a3[g * 4 + 2]);
            a3[g * 4 + 3] = fmaf(wv, x.w, a3[g * 4 + 3]);
        }
    }
    {
        float t = bl[o3];
        float m = -3.4e38f;
#pragma unroll
        for (int j = 0; j < 32; ++j) {
            float y = a3[j] + t;
            y = y > 0.f ? y : 0.2f * y;
            m = fmaxf(m, y);
        }
        out[((size_t)b * 128 + o3) * NPOINT + q0 + kb3] = m;
    }
}

// ---------------------------------------------------------------------------
extern "C" void kernel_launch(void* const* d_in, const int* in_sizes, int n_in,
                              void* d_out, int out_size, void* d_ws, size_t ws_size,
                              hipStream_t stream) {
    (void)in_sizes; (void)n_in; (void)out_size; (void)ws_size;
    const float* feats  = (const float*)d_in[0];
    const float* points = (const float*)d_in[1];
    const float* w1  = (const float*)d_in[2];
    const float* b1  = (const float*)d_in[3];
    const float* g1  = (const float*)d_in[4];
    const float* bb1 = (const float*)d_in[5];
    const float* m1  = (const float*)d_in[6];
    const float* v1  = (const float*)d_in[7];
    const float* w2  = (const float*)d_in[8];
    const float* b2  = (const float*)d_in[9];
    const float* g2  = (const float*)d_in[10];
    const float* bb2 = (const float*)d_in[11];
    const float* m2  = (const float*)d_in[12];
    const float* v2  = (const float*)d_in[13];
    const float* w3  = (const float*)d_in[14];
    const float* b3  = (const float*)d_in[15];
    const float* g3  = (const float*)d_in[16];
    const float* bb3 = (const float*)d_in[17];
    const float* m3  = (const float*)d_in[18];
    const float* v3  = (const float*)d_in[19];

    float* out = (float*)d_out;
    char*  ws  = (char*)d_ws;
    int*   fidx    = (int*)ws;                           // 8*2048 int = 64 KB
    int*   ballidx = (int*)(ws + 65536);                 // 8*2048*32 int = 2 MB
    float* wbuf    = (float*)(ws + 65536 + 2097152);     // 16832 floats
    float* out_xyz = out + (size_t)NBATCH * 128 * NPOINT;

    hipLaunchKernelGGL(prep_kernel, dim3(66), dim3(256), 0, stream,
                       w1, b1, g1, bb1, m1, v1, w2, b2, g2, bb2, m2, v2,
                       w3, b3, g3, bb3, m3, v3, wbuf);
    hipLaunchKernelGGL(fps_kernel, dim3(NBATCH), dim3(512), 0, stream, points, fidx);
    hipLaunchKernelGGL(bq_kernel, dim3(16384 / 4), dim3(256), 0, stream,
                       points, fidx, ballidx, out_xyz);
    hipLaunchKernelGGL(mlp_kernel, dim3(NBATCH * 1024), dim3(256), 0, stream,
                       feats, points, fidx, ballidx, wbuf, out);
}

// Round 15
// 3053.179 us; speedup vs baseline: 1.6032x; 1.0028x over previous
//
#include <hip/hip_runtime.h>
#include <cstdint>
#include <cstddef>

#define NBATCH  8
#define NPTS    8192
#define NFEAT   64
#define NPOINT  2048
#define NSAMPLE 32

// ---------------------------------------------------------------------------
// prep: fold BN into weights (y = dot*s + t), transpose to [c][o]
// ---------------------------------------------------------------------------
__global__ void prep_kernel(const float* __restrict__ w1, const float* __restrict__ b1,
                            const float* __restrict__ g1, const float* __restrict__ bb1,
                            const float* __restrict__ m1, const float* __restrict__ v1,
                            const float* __restrict__ w2, const float* __restrict__ b2,
                            const float* __restrict__ g2, const float* __restrict__ bb2,
                            const float* __restrict__ m2, const float* __restrict__ v2,
                            const float* __restrict__ w3, const float* __restrict__ b3,
                            const float* __restrict__ g3, const float* __restrict__ bb3,
                            const float* __restrict__ m3, const float* __restrict__ v3,
                            float* __restrict__ wbuf) {
    int i = blockIdx.x * 256 + threadIdx.x;
    if (i < 4288) {
        int o = i & 63, c = i >> 6;
        float s = g1[o] / sqrtf(v1[o] + 1e-5f);
        wbuf[i] = w1[o * 67 + c] * s;
    } else if (i < 4352) {
        int o = i - 4288;
        float s = g1[o] / sqrtf(v1[o] + 1e-5f);
        wbuf[i] = (b1[o] - m1[o]) * s + bb1[o];
    } else if (i < 8448) {
        int j = i - 4352; int o = j & 63, c = j >> 6;
        float s = g2[o] / sqrtf(v2[o] + 1e-5f);
        wbuf[i] = w2[o * 64 + c] * s;
    } else if (i < 8512) {
        int o = i - 8448;
        float s = g2[o] / sqrtf(v2[o] + 1e-5f);
        wbuf[i] = (b2[o] - m2[o]) * s + bb2[o];
    } else if (i < 16704) {
        int j = i - 8512; int o = j & 127, c = j >> 7;
        float s = g3[o] / sqrtf(v3[o] + 1e-5f);
        wbuf[i] = w3[o * 64 + c] * s;
    } else if (i < 16832) {
        int o = i - 16704;
        float s = g3[o] / sqrtf(v3[o] + 1e-5f);
        wbuf[i] = (b3[o] - m3[o]) * s + bb3[o];
    }
}

// ---------------------------------------------------------------------------
// FPS — R14 structure (VGPR=88 resident) with stage-2 replaced by a single
// LDS u64 atomicMax per wave. key = (bits(v)<<13)|(8191-o): v>=0 so f32 bits
// are order-monotone; max key == (max v, tie -> min o) == numpy argmax
// (same packing validated in R5). 4-slot rotation: iter i uses pk[i&3],
// tid0 zeroes pk[(i+2)&3] pre-barrier (its readers finished 2 barriers ago).
// Post-barrier: one broadcast u64 read + decode -> w, then indexed centroid
// read. Deletes the 3-step shfl_xor butterfly from the critical path.
// Exact IEEE f32 recipe + min-index tie-breaks (bit-exact R1-R14).
// ---------------------------------------------------------------------------
__global__ __launch_bounds__(512, 2) void fps_kernel(const float* __restrict__ points,
                                                     int* __restrict__ fidx) {
    const int b = blockIdx.x;
    const int tid = threadIdx.x;
    const int lane = tid & 63;
    const float* __restrict__ pxg = points + (size_t)b * 3 * NPTS;
    const float* __restrict__ pyg = pxg + NPTS;
    const float* __restrict__ pzg = pyg + NPTS;

    __shared__ float lx[NPTS];     // 32 KB
    __shared__ float ly[NPTS];     // 32 KB
    __shared__ float lz[NPTS];     // 32 KB
    __shared__ unsigned long long pk[4];

    float px[16], py[16], pz[16], dd[16];
#pragma unroll
    for (int j = 0; j < 16; ++j) {
        int n = tid + 512 * j;
        px[j] = pxg[n]; py[j] = pyg[n]; pz[j] = pzg[n];
        lx[n] = px[j];  ly[n] = py[j];  lz[n] = pz[j];
        dd[j] = 1e10f;
    }
    if (tid < 4) pk[tid] = 0ull;
    if (tid == 0) fidx[b * NPOINT + 0] = 0;
    __syncthreads();
    int w = 0;
    for (int i = 1; i < NPOINT; ++i) {
        // broadcast read of current centroid from LDS (same addr all lanes)
        const float cx = lx[w], cy = ly[w], cz = lz[w];
        float bestd = -1.0f; int besti = 0;
#pragma unroll
        for (int j = 0; j < 16; ++j) {
            float dx = __fsub_rn(px[j], cx);
            float dy = __fsub_rn(py[j], cy);
            float dz = __fsub_rn(pz[j], cz);
            float d  = __fadd_rn(__fadd_rn(__fmul_rn(dx, dx), __fmul_rn(dy, dy)),
                                 __fmul_rn(dz, dz));
            float nd = fminf(dd[j], d);
            dd[j] = nd;
            bool better = (nd > bestd);   // strict > keeps smaller idx on tie
            bestd = better ? nd : bestd;
            besti = better ? (tid + 512 * j) : besti;
        }
        // wave-level argmax reduce (max dist, tie -> min idx)
#pragma unroll
        for (int off = 32; off >= 1; off >>= 1) {
            float od = __shfl_down(bestd, off);
            int   oi = __shfl_down(besti, off);
            bool take = (od > bestd) || (od == bestd && oi < besti);
            bestd = take ? od : bestd;
            besti = take ? oi : besti;
        }
        const int slot = i & 3;
        if (lane == 0) {
            unsigned long long key =
                ((unsigned long long)(unsigned)__float_as_int(bestd) << 13)
              | (unsigned long long)(8191 - besti);
            atomicMax(&pk[slot], key);
        }
        if (tid == 0) pk[(i + 2) & 3] = 0ull;   // readers done 2 barriers ago
        __syncthreads();
        unsigned long long K = pk[slot];        // broadcast u64 read
        w = 8191 - (int)(K & 8191ull);
        if (tid == 0) fidx[b * NPOINT + i] = w;
    }
}

// ---------------------------------------------------------------------------
// Ball query: one wave per query. d = (qq+pp) - 2*qp, compare vs 0.04f.
// qp is the K=3 einsum/dot -> ascending FMA chain (verified exact in R1).
// ---------------------------------------------------------------------------
__global__ __launch_bounds__(256) void bq_kernel(const float* __restrict__ points,
                                                 const int* __restrict__ fidx,
                                                 int* __restrict__ ballidx,
                                                 float* __restrict__ out_xyz) {
    const int lane = threadIdx.x & 63;
    const int gw = (blockIdx.x << 2) + (threadIdx.x >> 6);
    const int b = gw >> 11;
    const int q = gw & 2047;
    const float* __restrict__ pxg = points + (size_t)b * 3 * NPTS;
    const float* __restrict__ pyg = pxg + NPTS;
    const float* __restrict__ pzg = pyg + NPTS;
    const int qi = fidx[b * NPOINT + q];
    const float qx = pxg[qi], qy = pyg[qi], qz = pzg[qi];
    const float qq = __fadd_rn(__fadd_rn(__fmul_rn(qx, qx), __fmul_rn(qy, qy)),
                               __fmul_rn(qz, qz));
    int* __restrict__ out = ballidx + ((size_t)(b * NPOINT + q)) * NSAMPLE;
    int have = 0;
    int first = -1;
    for (int base = 0; base < NPTS && have < NSAMPLE; base += 64) {
        const int n = base + lane;
        float x = pxg[n], y = pyg[n], z = pzg[n];
        float pp = __fadd_rn(__fadd_rn(__fmul_rn(x, x), __fmul_rn(y, y)), __fmul_rn(z, z));
        float qp = __builtin_fmaf(qz, z, __builtin_fmaf(qy, y, __fmul_rn(qx, x)));
        float d  = __fsub_rn(__fadd_rn(qq, pp), __fmul_rn(2.0f, qp));
        bool inb = d < 0.04f;   // f32(0.2*0.2) == 0.04f
        unsigned long long mask = __ballot(inb);
        if (mask) {
            if (first < 0) first = base + __ffsll(mask) - 1;
            if (inb) {
                int slot = have + (int)__popcll(mask & ((1ull << lane) - 1ull));
                if (slot < NSAMPLE) out[slot] = n;
            }
            have += (int)__popcll(mask);
        }
    }
    for (int s = have + lane; s < NSAMPLE; s += 64) out[s] = first;
    if (lane == 0) {
        float* o0 = out_xyz + (size_t)b * 3 * NPOINT + q;
        o0[0] = qx; o0[NPOINT] = qy; o0[2 * NPOINT] = qz;
    }
}

// ---------------------------------------------------------------------------
// Fused gather + 3-layer MLP + max-pool, TWO queries per block (k = 64).
// Layers 1/2: 2-output x 8-sample register tile (R13-validated, bit-exact).
// ---------------------------------------------------------------------------
#define XS2 68   // 64 + 4 pad (16B-aligned rows)
__global__ __launch_bounds__(256) void mlp_kernel(const float* __restrict__ feats,
                                                  const float* __restrict__ points,
                                                  const int* __restrict__ fidx,
                                                  const int* __restrict__ ballidx,
                                                  const float* __restrict__ wbuf,
                                                  float* __restrict__ out) {
    __shared__ __align__(16) float xT[67 * XS2];   // [c][k], reused for y2
    __shared__ __align__(16) float yA[64 * XS2];   // y1
    __shared__ __align__(16) float wl[8192];       // current layer weights [c][o]
    __shared__ float bl[128];
    __shared__ int   il[64];
    __shared__ float qv[6];
    const int tid = threadIdx.x;
    const int blk = blockIdx.x;
    const int b = blk >> 10;            // 1024 query-pairs per batch
    const int q0 = (blk & 1023) * 2;
    const float* __restrict__ pb = points + (size_t)b * 3 * NPTS;
    const float4* __restrict__ wb4 = (const float4*)wbuf;

    if (tid < 64)
        il[tid] = ballidx[((size_t)(b * NPOINT + q0 + (tid >> 5))) * NSAMPLE + (tid & 31)];
    if (tid < 6) {
        int qq_ = tid / 3, dim = tid % 3;
        qv[tid] = pb[(size_t)dim * NPTS + fidx[b * NPOINT + q0 + qq_]];
    }
    // stage layer-1 weights (4288 floats = 1072 float4)
    for (int i = tid; i < 1072; i += 256) ((float4*)wl)[i] = wb4[i];
    if (tid < 64) bl[tid] = wbuf[4288 + tid];
    __syncthreads();

    // build xT: rows 0..2 = grouped_xyz, rows 3..66 = gathered features
    if (tid < 64) {
        int n = il[tid], qsel = tid >> 5;
        xT[0 * XS2 + tid] = pb[n] - qv[qsel * 3 + 0];
        xT[1 * XS2 + tid] = pb[NPTS + n] - qv[qsel * 3 + 1];
        xT[2 * XS2 + tid] = pb[2 * NPTS + n] - qv[qsel * 3 + 2];
    }
    {
        int k = tid & 63, fg = tid >> 6;          // 4 groups x 16 feature rows
        int n = il[k];
        const float* fb = feats + ((size_t)b * NFEAT + fg * 16) * NPTS + n;
#pragma unroll
        for (int u = 0; u < 16; ++u) xT[(3 + fg * 16 + u) * XS2 + k] = fb[(size_t)u * NPTS];
    }
    __syncthreads();

    const int op = (tid & 31) * 2;    // output pair {op, op+1}
    const int sg = tid >> 5;          // sample group (0..7), 8 samples each
    float acc0[8], acc1[8];
    // ---- layer 1: 67 -> 64 (2-output x 8-sample register tile) ----
#pragma unroll
    for (int j = 0; j < 8; ++j) { acc0[j] = 0.f; acc1[j] = 0.f; }
    for (int c = 0; c < 67; ++c) {
        float2 wv2 = *(const float2*)&wl[c * 64 + op];
        const float4* xp = (const float4*)&xT[c * XS2 + sg * 8];
        float4 a0 = xp[0], a1 = xp[1];
        acc0[0] = fmaf(wv2.x, a0.x, acc0[0]); acc0[1] = fmaf(wv2.x, a0.y, acc0[1]);
        acc0[2] = fmaf(wv2.x, a0.z, acc0[2]); acc0[3] = fmaf(wv2.x, a0.w, acc0[3]);
        acc0[4] = fmaf(wv2.x, a1.x, acc0[4]); acc0[5] = fmaf(wv2.x, a1.y, acc0[5]);
        acc0[6] = fmaf(wv2.x, a1.z, acc0[6]); acc0[7] = fmaf(wv2.x, a1.w, acc0[7]);
        acc1[0] = fmaf(wv2.y, a0.x, acc1[0]); acc1[1] = fmaf(wv2.y, a0.y, acc1[1]);
        acc1[2] = fmaf(wv2.y, a0.z, acc1[2]); acc1[3] = fmaf(wv2.y, a0.w, acc1[3]);
        acc1[4] = fmaf(wv2.y, a1.x, acc1[4]); acc1[5] = fmaf(wv2.y, a1.y, acc1[5]);
        acc1[6] = fmaf(wv2.y, a1.z, acc1[6]); acc1[7] = fmaf(wv2.y, a1.w, acc1[7]);
    }
    {
        float t0 = bl[op], t1 = bl[op + 1];
#pragma unroll
        for (int j = 0; j < 8; ++j) {
            float y0 = acc0[j] + t0;
            y0 = y0 > 0.f ? y0 : 0.2f * y0;
            yA[op * XS2 + sg * 8 + j] = y0;
            float y1 = acc1[j] + t1;
            y1 = y1 > 0.f ? y1 : 0.2f * y1;
            yA[(op + 1) * XS2 + sg * 8 + j] = y1;
        }
    }
    __syncthreads();
    for (int i = tid; i < 1024; i += 256) ((float4*)wl)[i] = wb4[1088 + i];
    if (tid < 64) bl[tid] = wbuf[8448 + tid];
    __syncthreads();

    // ---- layer 2: 64 -> 64 (same 2x8 tile) ----
#pragma unroll
    for (int j = 0; j < 8; ++j) { acc0[j] = 0.f; acc1[j] = 0.f; }
    for (int c = 0; c < 64; ++c) {
        float2 wv2 = *(const float2*)&wl[c * 64 + op];
        const float4* xp = (const float4*)&yA[c * XS2 + sg * 8];
        float4 a0 = xp[0], a1 = xp[1];
        acc0[0] = fmaf(wv2.x, a0.x, acc0[0]); acc0[1] = fmaf(wv2.x, a0.y, acc0[1]);
        acc0[2] = fmaf(wv2.x, a0.z, acc0[2]); acc0[3] = fmaf(wv2.x, a0.w, acc0[3]);
        acc0[4] = fmaf(wv2.x, a1.x, acc0[4]); acc0[5] = fmaf(wv2.x, a1.y, acc0[5]);
        acc0[6] = fmaf(wv2.x, a1.z, acc0[6]); acc0[7] = fmaf(wv2.x, a1.w, acc0[7]);
        acc1[0] = fmaf(wv2.y, a0.x, acc1[0]); acc1[1] = fmaf(wv2.y, a0.y, acc1[1]);
        acc1[2] = fmaf(wv2.y, a0.z, acc1[2]); acc1[3] = fmaf(wv2.y, a0.w, acc1[3]);
        acc1[4] = fmaf(wv2.y, a1.x, acc1[4]); acc1[5] = fmaf(wv2.y, a1.y, acc1[5]);
        acc1[6] = fmaf(wv2.y, a1.z, acc1[6]); acc1[7] = fmaf(wv2.y, a1.w, acc1[7]);
    }
    {
        float t0 = bl[op], t1 = bl[op + 1];
#pragma unroll
        for (int j = 0; j < 8; ++j) {
            float y0 = acc0[j] + t0;
            y0 = y0 > 0.f ? y0 : 0.2f * y0;
            xT[op * XS2 + sg * 8 + j] = y0;     // y2 into xT (reads all done)
            float y1 = acc1[j] + t1;
            y1 = y1 > 0.f ? y1 : 0.2f * y1;
            xT[(op + 1) * XS2 + sg * 8 + j] = y1;
        }
    }
    __syncthreads();
    for (int i = tid; i < 2048; i += 256) ((float4*)wl)[i] = wb4[2128 + i];
    if (tid < 128) bl[tid] = wbuf[16704 + tid];
    __syncthreads();

    // ---- layer 3: 64 -> 128, max over this thread's query (32 samples) ----
    const int o3 = tid & 127, kb3 = tid >> 7;   // kb3 = query select
    float a3[32];
#pragma unroll
    for (int j = 0; j < 32; ++j) a3[j] = 0.f;
    for (int c = 0; c < 64; ++c) {
        float wv = wl[c * 128 + o3];
        const float4* xp = (const float4*)&xT[c * XS2 + kb3 * 32];
#pragma unroll
        for (int g = 0; g < 8; ++g) {
            float4 x = xp[g];
            a3[g * 4 + 0] = fmaf(wv, x.x, a3[g * 4 + 0]);
            a3[g * 4 + 1] = fmaf(wv, x.y, a3[g * 4 + 1]);
            a3[g * 4 + 2] = fmaf(wv, x.z, a3[g * 4 + 2]);
            a3[g * 4 + 3] = fmaf(wv, x.w, a3[g * 4 + 3]);
        }
    }
    {
        float t = bl[o3];
        float m = -3.4e38f;
#pragma unroll
        for (int j = 0; j < 32; ++j) {
            float y = a3[j] + t;
            y = y > 0.f ? y : 0.2f * y;
            m = fmaxf(m, y);
        }
        out[((size_t)b * 128 + o3) * NPOINT + q0 + kb3] = m;
    }
}

// ---------------------------------------------------------------------------
extern "C" void kernel_launch(void* const* d_in, const int* in_sizes, int n_in,
                              void* d_out, int out_size, void* d_ws, size_t ws_size,
                              hipStream_t stream) {
    (void)in_sizes; (void)n_in; (void)out_size; (void)ws_size;
    const float* feats  = (const float*)d_in[0];
    const float* points = (const float*)d_in[1];
    const float* w1  = (const float*)d_in[2];
    const float* b1  = (const float*)d_in[3];
    const float* g1  = (const float*)d_in[4];
    const float* bb1 = (const float*)d_in[5];
    const float* m1  = (const float*)d_in[6];
    const float* v1  = (const float*)d_in[7];
    const float* w2  = (const float*)d_in[8];
    const float* b2  = (const float*)d_in[9];
    const float* g2  = (const float*)d_in[10];
    const float* bb2 = (const float*)d_in[11];
    const float* m2  = (const float*)d_in[12];
    const float* v2  = (const float*)d_in[13];
    const float* w3  = (const float*)d_in[14];
    const float* b3  = (const float*)d_in[15];
    const float* g3  = (const float*)d_in[16];
    const float* bb3 = (const float*)d_in[17];
    const float* m3  = (const float*)d_in[18];
    const float* v3  = (const float*)d_in[19];

    float* out = (float*)d_out;
    char*  ws  = (char*)d_ws;
    int*   fidx    = (int*)ws;                           // 8*2048 int = 64 KB
    int*   ballidx = (int*)(ws + 65536);                 // 8*2048*32 int = 2 MB
    float* wbuf    = (float*)(ws + 65536 + 2097152);     // 16832 floats
    float* out_xyz = out + (size_t)NBATCH * 128 * NPOINT;

    hipLaunchKernelGGL(prep_kernel, dim3(66), dim3(256), 0, stream,
                       w1, b1, g1, bb1, m1, v1, w2, b2, g2, bb2, m2, v2,
                       w3, b3, g3, bb3, m3, v3, wbuf);
    hipLaunchKernelGGL(fps_kernel, dim3(NBATCH), dim3(512), 0, stream, points, fidx);
    hipLaunchKernelGGL(bq_kernel, dim3(16384 / 4), dim3(256), 0, stream,
                       points, fidx, ballidx, out_xyz);
    hipLaunchKernelGGL(mlp_kernel, dim3(NBATCH * 1024), dim3(256), 0, stream,
                       feats, points, fidx, ballidx, wbuf, out);
}